// Round 1
// baseline (7773.287 us; speedup 1.0000x reference)
//
#include <hip/hip_runtime.h>
#include <math.h>

// ---------------------------------------------------------------------------
// LGConv: out[dst] += x[src], scatter-atomic version (round 0 baseline).
// One thread per (edge, float4-chunk). x rows are L3-resident (<=51MB).
// ---------------------------------------------------------------------------
__global__ __launch_bounds__(256)
void lgconv_scatter(const float* __restrict__ x,
                    const int* __restrict__ src,
                    const int* __restrict__ dst,
                    float* __restrict__ out,
                    int E, int D) {
    const int CH = D >> 2;                 // float4 chunks per row (12 or 32)
    int idx = blockIdx.x * 256 + threadIdx.x;
    int total = E * CH;
    if (idx >= total) return;
    int e = idx / CH;
    int c = idx - e * CH;
    int s = src[e];
    int d = dst[e];
    const float4 v = *(const float4*)(x + (size_t)s * D + (size_t)c * 4);
    float* o = out + (size_t)d * D + (size_t)c * 4;
    atomicAdd(o + 0, v.x);
    atomicAdd(o + 1, v.y);
    atomicAdd(o + 2, v.z);
    atomicAdd(o + 3, v.w);
}

// ---------------------------------------------------------------------------
// Fused 2-layer MLP over a 16-row tile:
//   Y = act2( relu( X @ Wa + ba ) @ Wb + bb ), optional row log_softmax.
// X is a virtual concat of up to 3 segments (never materialized).
// LDS tiles are stored transposed [k][row] with pad 20 so the inner loop is
// one broadcast ds_read_b128 (rows) + one coalesced float4 W load + 16 FMA.
// ---------------------------------------------------------------------------
template<int OUT2, bool RELU2, bool LSM>
__global__ __launch_bounds__(256)
void fused_mlp(const float* __restrict__ segA, int lenA,
               const float* __restrict__ segB, int lenB,
               const float* __restrict__ segC, int lenC,
               const float* __restrict__ Wa, const float* __restrict__ ba,
               const float* __restrict__ Wb, const float* __restrict__ bb,
               float* __restrict__ out, int n) {
    const int K1 = lenA + lenB + lenC;      // <= 304
    __shared__ float xs[304][20];           // [k][row], 16B-aligned float4 rows
    __shared__ float hid[256][20];          // stage-1 output, same layout

    const int tid  = threadIdx.x;
    const int row0 = blockIdx.x * 16;

    // ---- load X tile (transposed) ----
    const int lAB = lenA + lenB;
    for (int l = tid; l < K1 * 16; l += 256) {
        int r = l / K1;
        int k = l - r * K1;
        int row = row0 + r;
        float v = 0.f;
        if (row < n) {
            if (k < lenA)      v = segA[(size_t)row * lenA + k];
            else if (k < lAB)  v = segB[(size_t)row * lenB + (k - lenA)];
            else               v = segC[(size_t)row * lenC + (k - lAB)];
        }
        xs[k][r] = v;
    }
    __syncthreads();

    // ---- stage 1: [16 x K1] @ [K1 x 256] + ba, ReLU -> hid ----
    {
        const int jc = tid & 63;            // cols jc*4 .. jc*4+3
        const int rg = tid >> 6;            // rows rg*4 .. rg*4+3
        float acc[4][4];
        #pragma unroll
        for (int c = 0; c < 4; ++c) {
            float b = ba[jc * 4 + c];
            acc[0][c] = b; acc[1][c] = b; acc[2][c] = b; acc[3][c] = b;
        }
        #pragma unroll 4
        for (int k = 0; k < K1; ++k) {
            const float4 xv = *(const float4*)&xs[k][rg * 4];
            const float4 wv = *(const float4*)&Wa[(size_t)k * 256 + jc * 4];
            acc[0][0] += xv.x * wv.x; acc[0][1] += xv.x * wv.y; acc[0][2] += xv.x * wv.z; acc[0][3] += xv.x * wv.w;
            acc[1][0] += xv.y * wv.x; acc[1][1] += xv.y * wv.y; acc[1][2] += xv.y * wv.z; acc[1][3] += xv.y * wv.w;
            acc[2][0] += xv.z * wv.x; acc[2][1] += xv.z * wv.y; acc[2][2] += xv.z * wv.z; acc[2][3] += xv.z * wv.w;
            acc[3][0] += xv.w * wv.x; acc[3][1] += xv.w * wv.y; acc[3][2] += xv.w * wv.z; acc[3][3] += xv.w * wv.w;
        }
        #pragma unroll
        for (int i = 0; i < 4; ++i)
            #pragma unroll
            for (int c = 0; c < 4; ++c)
                hid[jc * 4 + c][rg * 4 + i] = fmaxf(acc[i][c], 0.f);
    }
    __syncthreads();

    // ---- stage 2 ----
    if (OUT2 == 128) {
        const int jc = tid & 31;            // cols jc*4 .. +3
        const int rg = tid >> 5;            // rows rg*2 .. +1 (8 groups)
        float acc[2][4];
        #pragma unroll
        for (int c = 0; c < 4; ++c) {
            float b = bb[jc * 4 + c];
            acc[0][c] = b; acc[1][c] = b;
        }
        #pragma unroll 4
        for (int k = 0; k < 256; ++k) {
            const float2 hv = *(const float2*)&hid[k][rg * 2];
            const float4 wv = *(const float4*)&Wb[(size_t)k * 128 + jc * 4];
            acc[0][0] += hv.x * wv.x; acc[0][1] += hv.x * wv.y; acc[0][2] += hv.x * wv.z; acc[0][3] += hv.x * wv.w;
            acc[1][0] += hv.y * wv.x; acc[1][1] += hv.y * wv.y; acc[1][2] += hv.y * wv.z; acc[1][3] += hv.y * wv.w;
        }
        #pragma unroll
        for (int i = 0; i < 2; ++i) {
            int row = row0 + rg * 2 + i;
            if (row < n) {
                #pragma unroll
                for (int c = 0; c < 4; ++c) {
                    float v = acc[i][c];
                    if (RELU2) v = fmaxf(v, 0.f);
                    out[(size_t)row * 128 + jc * 4 + c] = v;
                }
            }
        }
    } else {
        // OUT2 == 40, fused log_softmax. One wave per 4 rows; lane = column.
        const int lane = tid & 63;
        const int wg   = tid >> 6;
        const bool valid = lane < 40;
        float bbv = valid ? bb[lane] : 0.f;
        float acc[4];
        #pragma unroll
        for (int i = 0; i < 4; ++i) acc[i] = bbv;
        #pragma unroll 4
        for (int k = 0; k < 256; ++k) {
            const float4 hv = *(const float4*)&hid[k][wg * 4];
            const float wv = valid ? Wb[(size_t)k * 40 + lane] : 0.f;
            acc[0] += hv.x * wv;
            acc[1] += hv.y * wv;
            acc[2] += hv.z * wv;
            acc[3] += hv.w * wv;
        }
        #pragma unroll
        for (int i = 0; i < 4; ++i) {
            int row = row0 + wg * 4 + i;
            float v = valid ? acc[i] : -INFINITY;
            float m = v;
            #pragma unroll
            for (int off = 32; off >= 1; off >>= 1)
                m = fmaxf(m, __shfl_xor(m, off));
            float e = valid ? __expf(acc[i] - m) : 0.f;
            float s = e;
            #pragma unroll
            for (int off = 32; off >= 1; off >>= 1)
                s += __shfl_xor(s, off);
            float res = acc[i] - m - __logf(s);
            if (valid && row < n)
                out[(size_t)row * 40 + lane] = res;
        }
    }
}

// ---------------------------------------------------------------------------
extern "C" void kernel_launch(void* const* d_in, const int* in_sizes, int n_in,
                              void* d_out, int out_size, void* d_ws, size_t ws_size,
                              hipStream_t stream) {
    const float* x   = (const float*)d_in[0];
    const int*   ei  = (const int*)d_in[1];
    const float* W1a = (const float*)d_in[2];
    const float* b1a = (const float*)d_in[3];
    const float* W1b = (const float*)d_in[4];
    const float* b1b = (const float*)d_in[5];
    const float* W2a = (const float*)d_in[6];
    const float* b2a = (const float*)d_in[7];
    const float* W2b = (const float*)d_in[8];
    const float* b2b = (const float*)d_in[9];
    const float* W3a = (const float*)d_in[10];
    const float* b3a = (const float*)d_in[11];
    const float* W3b = (const float*)d_in[12];
    const float* b3b = (const float*)d_in[13];
    float* out = (float*)d_out;

    const int E = in_sizes[1] / 2;
    const int N = in_sizes[0] / 48;
    const int* src = ei;
    const int* dst = ei + E;

    // workspace layout (all f32)
    float* c1 = (float*)d_ws;                  // N*48
    float* h1 = c1 + (size_t)N * 48;           // N*128
    float* c2 = h1 + (size_t)N * 128;          // N*128
    float* h2 = c2 + (size_t)N * 128;          // N*128
    float* c3 = c2;                            // reuse c2 slot (dead by then)

    const int nblk_mlp = (N + 15) / 16;

    // ---- layer 1 ----
    hipMemsetAsync(c1, 0, (size_t)N * 48 * sizeof(float), stream);
    {
        int total = E * (48 / 4);
        lgconv_scatter<<<(total + 255) / 256, 256, 0, stream>>>(x, src, dst, c1, E, 48);
    }
    fused_mlp<128, true, false><<<nblk_mlp, 256, 0, stream>>>(
        c1, 48, x, 48, nullptr, 0, W1a, b1a, W1b, b1b, h1, N);

    // ---- layer 2 ----
    hipMemsetAsync(c2, 0, (size_t)N * 128 * sizeof(float), stream);
    {
        int total = E * (128 / 4);
        lgconv_scatter<<<(total + 255) / 256, 256, 0, stream>>>(h1, src, dst, c2, E, 128);
    }
    fused_mlp<128, true, false><<<nblk_mlp, 256, 0, stream>>>(
        c2, 128, h1, 128, x, 48, W2a, b2a, W2b, b2b, h2, N);

    // ---- layer 3 ----
    hipMemsetAsync(c3, 0, (size_t)N * 128 * sizeof(float), stream);
    {
        int total = E * (128 / 4);
        lgconv_scatter<<<(total + 255) / 256, 256, 0, stream>>>(h2, src, dst, c3, E, 128);
    }
    fused_mlp<40, false, true><<<nblk_mlp, 256, 0, stream>>>(
        c3, 128, h2, 128, x, 48, W3a, b3a, W3b, b3b, out, N);
}

// Round 2
// 1811.293 us; speedup vs baseline: 4.2916x; 4.2916x over previous
//
#include <hip/hip_runtime.h>
#include <math.h>

// ===========================================================================
// CSR build (by dst), rebuilt every launch (graph-capture safe, ws re-poisoned)
// ===========================================================================
__global__ __launch_bounds__(256)
void deg_hist(const int* __restrict__ dst, int* __restrict__ deg, int E) {
    int i = blockIdx.x * 256 + threadIdx.x;
    if (i < E) atomicAdd(&deg[dst[i]], 1);
}

// per-block sums of deg, 1024 elements / block (256 thr x 4)
__global__ __launch_bounds__(256)
void scan_block_sums(const int* __restrict__ deg, int* __restrict__ bsum, int N) {
    __shared__ int sh[256];
    int base = blockIdx.x * 1024 + threadIdx.x * 4;
    int s = 0;
    #pragma unroll
    for (int k = 0; k < 4; ++k) {
        int i = base + k;
        if (i < N) s += deg[i];
    }
    sh[threadIdx.x] = s;
    __syncthreads();
    for (int off = 128; off >= 1; off >>= 1) {
        if (threadIdx.x < off) sh[threadIdx.x] += sh[threadIdx.x + off];
        __syncthreads();
    }
    if (threadIdx.x == 0) bsum[blockIdx.x] = sh[0];
}

// exclusive scan of block sums (nb <= 256), single block
__global__ __launch_bounds__(256)
void scan_bsums(int* __restrict__ bsum, int nb) {
    __shared__ int sh[256];
    int t = threadIdx.x;
    int v = (t < nb) ? bsum[t] : 0;
    sh[t] = v;
    __syncthreads();
    // Hillis-Steele inclusive
    for (int off = 1; off < 256; off <<= 1) {
        int add = (t >= off) ? sh[t - off] : 0;
        __syncthreads();
        sh[t] += add;
        __syncthreads();
    }
    if (t < nb) bsum[t] = sh[t] - v;   // exclusive
}

// final: block-local exclusive scan + block offset -> rowptr, cursor
__global__ __launch_bounds__(256)
void scan_finalize(const int* __restrict__ deg, const int* __restrict__ bsum,
                   int* __restrict__ rowptr, int* __restrict__ cursor, int N) {
    __shared__ int sh[256];
    int t = threadIdx.x;
    int base = blockIdx.x * 1024 + t * 4;
    int loc[4];
    int s = 0;
    #pragma unroll
    for (int k = 0; k < 4; ++k) {
        int i = base + k;
        loc[k] = (i < N) ? deg[i] : 0;
        s += loc[k];
    }
    sh[t] = s;
    __syncthreads();
    for (int off = 1; off < 256; off <<= 1) {
        int add = (t >= off) ? sh[t - off] : 0;
        __syncthreads();
        sh[t] += add;
        __syncthreads();
    }
    int run = bsum[blockIdx.x] + sh[t] - s;   // exclusive prefix for this thread
    #pragma unroll
    for (int k = 0; k < 4; ++k) {
        int i = base + k;
        if (i < N) { rowptr[i] = run; cursor[i] = run; }
        run += loc[k];
    }
}

__global__ __launch_bounds__(256)
void csr_scatter(const int* __restrict__ src, const int* __restrict__ dst,
                 int* __restrict__ cursor, int* __restrict__ csr_src, int E) {
    int e = blockIdx.x * 256 + threadIdx.x;
    if (e < E) {
        int pos = atomicAdd(&cursor[dst[e]], 1);
        csr_src[pos] = src[e];
    }
}

// ===========================================================================
// LGConv gather: LPN lanes per node, lane = float4 chunk. No atomics.
// ===========================================================================
template<int D, int LPN>
__global__ __launch_bounds__(256)
void lgconv_gather(const float* __restrict__ x,
                   const int* __restrict__ rowptr,
                   const int* __restrict__ deg,
                   const int* __restrict__ csr_src,
                   float* __restrict__ out, int N) {
    const int g    = (blockIdx.x * 256 + threadIdx.x) / LPN;
    const int lane = threadIdx.x & (LPN - 1);
    if (g >= N) return;
    const int CH = D / 4;
    const int start = rowptr[g];
    const int dg    = deg[g];
    if (lane < CH) {
        float4 acc = make_float4(0.f, 0.f, 0.f, 0.f);
        int j = 0;
        for (; j + 1 < dg; j += 2) {
            int s0 = csr_src[start + j];
            int s1 = csr_src[start + j + 1];
            const float4 v0 = *(const float4*)(x + (size_t)s0 * D + lane * 4);
            const float4 v1 = *(const float4*)(x + (size_t)s1 * D + lane * 4);
            acc.x += v0.x; acc.y += v0.y; acc.z += v0.z; acc.w += v0.w;
            acc.x += v1.x; acc.y += v1.y; acc.z += v1.z; acc.w += v1.w;
        }
        if (j < dg) {
            int s0 = csr_src[start + j];
            const float4 v0 = *(const float4*)(x + (size_t)s0 * D + lane * 4);
            acc.x += v0.x; acc.y += v0.y; acc.z += v0.z; acc.w += v0.w;
        }
        *(float4*)(out + (size_t)g * D + lane * 4) = acc;
    }
}

// ===========================================================================
// Fused 2-layer MLP over a 16-row tile (unchanged from round 1)
// ===========================================================================
template<int OUT2, bool RELU2, bool LSM>
__global__ __launch_bounds__(256)
void fused_mlp(const float* __restrict__ segA, int lenA,
               const float* __restrict__ segB, int lenB,
               const float* __restrict__ segC, int lenC,
               const float* __restrict__ Wa, const float* __restrict__ ba,
               const float* __restrict__ Wb, const float* __restrict__ bb,
               float* __restrict__ out, int n) {
    const int K1 = lenA + lenB + lenC;      // <= 304
    __shared__ float xs[304][20];
    __shared__ float hid[256][20];

    const int tid  = threadIdx.x;
    const int row0 = blockIdx.x * 16;

    const int lAB = lenA + lenB;
    for (int l = tid; l < K1 * 16; l += 256) {
        int r = l / K1;
        int k = l - r * K1;
        int row = row0 + r;
        float v = 0.f;
        if (row < n) {
            if (k < lenA)      v = segA[(size_t)row * lenA + k];
            else if (k < lAB)  v = segB[(size_t)row * lenB + (k - lenA)];
            else               v = segC[(size_t)row * lenC + (k - lAB)];
        }
        xs[k][r] = v;
    }
    __syncthreads();

    {
        const int jc = tid & 63;
        const int rg = tid >> 6;
        float acc[4][4];
        #pragma unroll
        for (int c = 0; c < 4; ++c) {
            float b = ba[jc * 4 + c];
            acc[0][c] = b; acc[1][c] = b; acc[2][c] = b; acc[3][c] = b;
        }
        #pragma unroll 4
        for (int k = 0; k < K1; ++k) {
            const float4 xv = *(const float4*)&xs[k][rg * 4];
            const float4 wv = *(const float4*)&Wa[(size_t)k * 256 + jc * 4];
            acc[0][0] += xv.x * wv.x; acc[0][1] += xv.x * wv.y; acc[0][2] += xv.x * wv.z; acc[0][3] += xv.x * wv.w;
            acc[1][0] += xv.y * wv.x; acc[1][1] += xv.y * wv.y; acc[1][2] += xv.y * wv.z; acc[1][3] += xv.y * wv.w;
            acc[2][0] += xv.z * wv.x; acc[2][1] += xv.z * wv.y; acc[2][2] += xv.z * wv.z; acc[2][3] += xv.z * wv.w;
            acc[3][0] += xv.w * wv.x; acc[3][1] += xv.w * wv.y; acc[3][2] += xv.w * wv.z; acc[3][3] += xv.w * wv.w;
        }
        #pragma unroll
        for (int i = 0; i < 4; ++i)
            #pragma unroll
            for (int c = 0; c < 4; ++c)
                hid[jc * 4 + c][rg * 4 + i] = fmaxf(acc[i][c], 0.f);
    }
    __syncthreads();

    if (OUT2 == 128) {
        const int jc = tid & 31;
        const int rg = tid >> 5;
        float acc[2][4];
        #pragma unroll
        for (int c = 0; c < 4; ++c) {
            float b = bb[jc * 4 + c];
            acc[0][c] = b; acc[1][c] = b;
        }
        #pragma unroll 4
        for (int k = 0; k < 256; ++k) {
            const float2 hv = *(const float2*)&hid[k][rg * 2];
            const float4 wv = *(const float4*)&Wb[(size_t)k * 128 + jc * 4];
            acc[0][0] += hv.x * wv.x; acc[0][1] += hv.x * wv.y; acc[0][2] += hv.x * wv.z; acc[0][3] += hv.x * wv.w;
            acc[1][0] += hv.y * wv.x; acc[1][1] += hv.y * wv.y; acc[1][2] += hv.y * wv.z; acc[1][3] += hv.y * wv.w;
        }
        #pragma unroll
        for (int i = 0; i < 2; ++i) {
            int row = row0 + rg * 2 + i;
            if (row < n) {
                #pragma unroll
                for (int c = 0; c < 4; ++c) {
                    float v = acc[i][c];
                    if (RELU2) v = fmaxf(v, 0.f);
                    out[(size_t)row * 128 + jc * 4 + c] = v;
                }
            }
        }
    } else {
        const int lane = tid & 63;
        const int wg   = tid >> 6;
        const bool valid = lane < 40;
        float bbv = valid ? bb[lane] : 0.f;
        float acc[4];
        #pragma unroll
        for (int i = 0; i < 4; ++i) acc[i] = bbv;
        #pragma unroll 4
        for (int k = 0; k < 256; ++k) {
            const float4 hv = *(const float4*)&hid[k][wg * 4];
            const float wv = valid ? Wb[(size_t)k * 40 + lane] : 0.f;
            acc[0] += hv.x * wv;
            acc[1] += hv.y * wv;
            acc[2] += hv.z * wv;
            acc[3] += hv.w * wv;
        }
        #pragma unroll
        for (int i = 0; i < 4; ++i) {
            int row = row0 + wg * 4 + i;
            float v = valid ? acc[i] : -INFINITY;
            float m = v;
            #pragma unroll
            for (int off = 32; off >= 1; off >>= 1)
                m = fmaxf(m, __shfl_xor(m, off));
            float e = valid ? __expf(acc[i] - m) : 0.f;
            float s = e;
            #pragma unroll
            for (int off = 32; off >= 1; off >>= 1)
                s += __shfl_xor(s, off);
            float res = acc[i] - m - __logf(s);
            if (valid && row < n)
                out[(size_t)row * 40 + lane] = res;
        }
    }
}

// ===========================================================================
extern "C" void kernel_launch(void* const* d_in, const int* in_sizes, int n_in,
                              void* d_out, int out_size, void* d_ws, size_t ws_size,
                              hipStream_t stream) {
    const float* x   = (const float*)d_in[0];
    const int*   ei  = (const int*)d_in[1];
    const float* W1a = (const float*)d_in[2];
    const float* b1a = (const float*)d_in[3];
    const float* W1b = (const float*)d_in[4];
    const float* b1b = (const float*)d_in[5];
    const float* W2a = (const float*)d_in[6];
    const float* b2a = (const float*)d_in[7];
    const float* W2b = (const float*)d_in[8];
    const float* b2b = (const float*)d_in[9];
    const float* W3a = (const float*)d_in[10];
    const float* b3a = (const float*)d_in[11];
    const float* W3b = (const float*)d_in[12];
    const float* b3b = (const float*)d_in[13];
    float* out = (float*)d_out;

    const int E = in_sizes[1] / 2;
    const int N = in_sizes[0] / 48;
    const int* src = ei;
    const int* dst = ei + E;

    // workspace layout (f32 / int32)
    float* c1 = (float*)d_ws;                  // N*48
    float* h1 = c1 + (size_t)N * 48;           // N*128
    float* c2 = h1 + (size_t)N * 128;          // N*128
    float* h2 = c2 + (size_t)N * 128;          // N*128
    float* c3 = c2;                            // reuse (dead by layer 3)
    int* deg     = (int*)(h2 + (size_t)N * 128);   // N
    int* rowptr  = deg + N;                        // N
    int* cursor  = rowptr + N;                     // N
    int* bsum    = cursor + N;                     // <=256
    int* csr_src = bsum + 256;                     // E

    const int nblk_mlp = (N + 15) / 16;
    const int nb_scan  = (N + 1023) / 1024;

    // ---- CSR build (once, reused by all 3 convs) ----
    hipMemsetAsync(deg, 0, (size_t)N * sizeof(int), stream);
    deg_hist<<<(E + 255) / 256, 256, 0, stream>>>(dst, deg, E);
    scan_block_sums<<<nb_scan, 256, 0, stream>>>(deg, bsum, N);
    scan_bsums<<<1, 256, 0, stream>>>(bsum, nb_scan);
    scan_finalize<<<nb_scan, 256, 0, stream>>>(deg, bsum, rowptr, cursor, N);
    csr_scatter<<<(E + 255) / 256, 256, 0, stream>>>(src, dst, cursor, csr_src, E);

    // ---- layer 1 ----
    lgconv_gather<48, 16><<<((size_t)N * 16 + 255) / 256, 256, 0, stream>>>(
        x, rowptr, deg, csr_src, c1, N);
    fused_mlp<128, true, false><<<nblk_mlp, 256, 0, stream>>>(
        c1, 48, x, 48, nullptr, 0, W1a, b1a, W1b, b1b, h1, N);

    // ---- layer 2 ----
    lgconv_gather<128, 32><<<((size_t)N * 32 + 255) / 256, 256, 0, stream>>>(
        h1, rowptr, deg, csr_src, c2, N);
    fused_mlp<128, true, false><<<nblk_mlp, 256, 0, stream>>>(
        c2, 128, h1, 128, x, 48, W2a, b2a, W2b, b2b, h2, N);

    // ---- layer 3 ----
    lgconv_gather<128, 32><<<((size_t)N * 32 + 255) / 256, 256, 0, stream>>>(
        h2, rowptr, deg, csr_src, c3, N);
    fused_mlp<40, false, true><<<nblk_mlp, 256, 0, stream>>>(
        c3, 128, h2, 128, x, 48, W3a, b3a, W3b, b3b, out, N);
}

// Round 4
// 625.022 us; speedup vs baseline: 12.4368x; 2.8980x over previous
//
#include <hip/hip_runtime.h>
#include <math.h>

typedef __attribute__((ext_vector_type(8)))  short s16x8;   // 8 bf16 (4 VGPRs)
typedef __attribute__((ext_vector_type(16))) float f32x16;  // MFMA 32x32 acc

__device__ inline float bf_lo(unsigned u) { return __uint_as_float(u << 16); }
__device__ inline float bf_hi(unsigned u) { return __uint_as_float(u & 0xffff0000u); }
__device__ inline unsigned short f2bf(float f) {           // RNE f32 -> bf16
    unsigned u = __float_as_uint(f);
    u += 0x7fffu + ((u >> 16) & 1u);
    return (unsigned short)(u >> 16);
}

// ===========================================================================
// CSR build (by dst) — unchanged from round 2 (verified)
// ===========================================================================
__global__ __launch_bounds__(256)
void deg_hist(const int* __restrict__ dst, int* __restrict__ deg, int E) {
    int i = blockIdx.x * 256 + threadIdx.x;
    if (i < E) atomicAdd(&deg[dst[i]], 1);
}

__global__ __launch_bounds__(256)
void scan_block_sums(const int* __restrict__ deg, int* __restrict__ bsum, int N) {
    __shared__ int sh[256];
    int base = blockIdx.x * 1024 + threadIdx.x * 4;
    int s = 0;
    #pragma unroll
    for (int k = 0; k < 4; ++k) { int i = base + k; if (i < N) s += deg[i]; }
    sh[threadIdx.x] = s;
    __syncthreads();
    for (int off = 128; off >= 1; off >>= 1) {
        if (threadIdx.x < off) sh[threadIdx.x] += sh[threadIdx.x + off];
        __syncthreads();
    }
    if (threadIdx.x == 0) bsum[blockIdx.x] = sh[0];
}

__global__ __launch_bounds__(256)
void scan_bsums(int* __restrict__ bsum, int nb) {
    __shared__ int sh[256];
    int t = threadIdx.x;
    int v = (t < nb) ? bsum[t] : 0;
    sh[t] = v;
    __syncthreads();
    for (int off = 1; off < 256; off <<= 1) {
        int add = (t >= off) ? sh[t - off] : 0;
        __syncthreads();
        sh[t] += add;
        __syncthreads();
    }
    if (t < nb) bsum[t] = sh[t] - v;
}

__global__ __launch_bounds__(256)
void scan_finalize(const int* __restrict__ deg, const int* __restrict__ bsum,
                   int* __restrict__ rowptr, int* __restrict__ cursor, int N) {
    __shared__ int sh[256];
    int t = threadIdx.x;
    int base = blockIdx.x * 1024 + t * 4;
    int loc[4];
    int s = 0;
    #pragma unroll
    for (int k = 0; k < 4; ++k) {
        int i = base + k;
        loc[k] = (i < N) ? deg[i] : 0;
        s += loc[k];
    }
    sh[t] = s;
    __syncthreads();
    for (int off = 1; off < 256; off <<= 1) {
        int add = (t >= off) ? sh[t - off] : 0;
        __syncthreads();
        sh[t] += add;
        __syncthreads();
    }
    int run = bsum[blockIdx.x] + sh[t] - s;
    #pragma unroll
    for (int k = 0; k < 4; ++k) {
        int i = base + k;
        if (i < N) { rowptr[i] = run; cursor[i] = run; }
        run += loc[k];
    }
}

__global__ __launch_bounds__(256)
void csr_scatter(const int* __restrict__ src, const int* __restrict__ dst,
                 int* __restrict__ cursor, int* __restrict__ csr_src, int E) {
    int e = blockIdx.x * 256 + threadIdx.x;
    if (e < E) {
        int pos = atomicAdd(&cursor[dst[e]], 1);
        csr_src[pos] = src[e];
    }
}

// ===========================================================================
// prep: f32 -> bf16; weight transpose [K][Nc] f32 -> [Np][K] bf16 (zero-pad)
// ===========================================================================
__global__ __launch_bounds__(256)
void f32_to_bf16k(const float* __restrict__ in, unsigned short* __restrict__ out, int n) {
    int i = blockIdx.x * 256 + threadIdx.x;
    if (i < n) out[i] = f2bf(in[i]);
}

__global__ __launch_bounds__(256)
void wt_transpose(const float* __restrict__ W, unsigned short* __restrict__ Wt,
                  int K, int Nc, int Np) {
    int idx = blockIdx.x * 256 + threadIdx.x;
    if (idx >= Np * K) return;
    int n = idx / K, k = idx - n * K;
    float v = (n < Nc) ? W[(size_t)k * Nc + n] : 0.f;
    Wt[idx] = f2bf(v);
}

// ===========================================================================
// LGConv gather, bf16 in/out, f32 accumulate. 8 channels (16B) per lane.
// ===========================================================================
template<int D, int LPN>
__global__ __launch_bounds__(256)
void lgconv_gather_bf16(const unsigned short* __restrict__ x,
                        const int* __restrict__ rowptr,
                        const int* __restrict__ deg,
                        const int* __restrict__ csr_src,
                        unsigned short* __restrict__ out, int N) {
    const int g    = (blockIdx.x * 256 + threadIdx.x) / LPN;
    const int lane = threadIdx.x & (LPN - 1);
    if (g >= N) return;
    if (lane * 8 >= D) return;
    const int start = rowptr[g];
    const int dg    = deg[g];
    float acc[8] = {0.f,0.f,0.f,0.f,0.f,0.f,0.f,0.f};
    int j = 0;
    for (; j + 1 < dg; j += 2) {
        int s0 = csr_src[start + j];
        int s1 = csr_src[start + j + 1];
        uint4 v0 = *(const uint4*)(x + (size_t)s0 * D + lane * 8);
        uint4 v1 = *(const uint4*)(x + (size_t)s1 * D + lane * 8);
        acc[0] += bf_lo(v0.x); acc[1] += bf_hi(v0.x);
        acc[2] += bf_lo(v0.y); acc[3] += bf_hi(v0.y);
        acc[4] += bf_lo(v0.z); acc[5] += bf_hi(v0.z);
        acc[6] += bf_lo(v0.w); acc[7] += bf_hi(v0.w);
        acc[0] += bf_lo(v1.x); acc[1] += bf_hi(v1.x);
        acc[2] += bf_lo(v1.y); acc[3] += bf_hi(v1.y);
        acc[4] += bf_lo(v1.z); acc[5] += bf_hi(v1.z);
        acc[6] += bf_lo(v1.w); acc[7] += bf_hi(v1.w);
    }
    if (j < dg) {
        int s0 = csr_src[start + j];
        uint4 v0 = *(const uint4*)(x + (size_t)s0 * D + lane * 8);
        acc[0] += bf_lo(v0.x); acc[1] += bf_hi(v0.x);
        acc[2] += bf_lo(v0.y); acc[3] += bf_hi(v0.y);
        acc[4] += bf_lo(v0.z); acc[5] += bf_hi(v0.z);
        acc[6] += bf_lo(v0.w); acc[7] += bf_hi(v0.w);
    }
    uint4 o;
    o.x = ((unsigned)f2bf(acc[1]) << 16) | f2bf(acc[0]);
    o.y = ((unsigned)f2bf(acc[3]) << 16) | f2bf(acc[2]);
    o.z = ((unsigned)f2bf(acc[5]) << 16) | f2bf(acc[4]);
    o.w = ((unsigned)f2bf(acc[7]) << 16) | f2bf(acc[6]);
    *(uint4*)(out + (size_t)g * D + lane * 8) = o;
}

// ===========================================================================
// Fused 2-layer MLP, bf16 MFMA (32x32x16), 64 rows/block, 4 waves.
//  stage1: [64 x K1] @ WaT[256][K1] -> relu -> hid (LDS bf16 [64][264])
//  stage2: hid @ WbT[OUTP][256] -> relu->bf16 out   (LSM=false, OUT=128)
//                                -> log_softmax f32 (LSM=true,  OUT=40 pad 64)
// A-frags straight from global (concat segments resolved at compile time).
// Layouts (measured, m74/m101): A[m][k]: m=lane&31, k=(lane>>5)*8+i ;
// B[k][n]: n=lane&31, same k ; C/D: col=lane&31, row=(t&3)+8*(t>>2)+4*(lane>>5).
// ===========================================================================
template<int LA, int LB, int LC, bool LSM>
__global__ __launch_bounds__(256)
void fused_mlp_mfma(const unsigned short* __restrict__ segA,
                    const unsigned short* __restrict__ segB,
                    const unsigned short* __restrict__ segC,
                    const unsigned short* __restrict__ WaT, const float* __restrict__ ba,
                    const unsigned short* __restrict__ WbT, const float* __restrict__ bb,
                    void* __restrict__ outv, int n) {
    constexpr int K1  = LA + LB + LC;       // 96 or 304
    constexpr int NS1 = K1 / 16;
    constexpr int K2P = 264;                // 256 + 8 (rows stay 16B-aligned)
    __shared__ __attribute__((aligned(16))) unsigned short hid[64 * K2P];

    const int tid  = threadIdx.x;
    const int wave = tid >> 6;
    const int lane = tid & 63;
    const int l31  = lane & 31;
    const int lh   = lane >> 5;
    const int row0 = blockIdx.x * 64;

    const int r0  = row0 + l31;
    const int r1  = r0 + 32;
    const int ra0 = (r0 < n) ? r0 : (n - 1);
    const int ra1 = (r1 < n) ? r1 : (n - 1);

    // ---------------- stage 1 ----------------
    f32x16 acc00 = {}, acc01 = {}, acc10 = {}, acc11 = {};
    const unsigned short* wa0 = WaT + (size_t)(wave * 64 + l31) * K1 + lh * 8;
    const unsigned short* wa1 = wa0 + (size_t)32 * K1;

    #pragma unroll
    for (int s = 0; s < NS1; ++s) {
        const int k0 = s * 16;              // compile-time; segment-uniform
        const unsigned short* ap;
        int strd, off;
        if (k0 < LA)           { ap = segA; strd = LA; off = k0; }
        else if (k0 < LA + LB) { ap = segB; strd = LB; off = k0 - LA; }
        else                   { ap = segC; strd = LC; off = k0 - LA - LB; }
        s16x8 a0 = *(const s16x8*)(ap + (size_t)ra0 * strd + off + lh * 8);
        s16x8 a1 = *(const s16x8*)(ap + (size_t)ra1 * strd + off + lh * 8);
        s16x8 b0 = *(const s16x8*)(wa0 + k0);
        s16x8 b1 = *(const s16x8*)(wa1 + k0);
        acc00 = __builtin_amdgcn_mfma_f32_32x32x16_bf16(a0, b0, acc00, 0, 0, 0);
        acc01 = __builtin_amdgcn_mfma_f32_32x32x16_bf16(a0, b1, acc01, 0, 0, 0);
        acc10 = __builtin_amdgcn_mfma_f32_32x32x16_bf16(a1, b0, acc10, 0, 0, 0);
        acc11 = __builtin_amdgcn_mfma_f32_32x32x16_bf16(a1, b1, acc11, 0, 0, 0);
    }

    // epilogue: + bias, relu -> hid[m][k] bf16
    {
        const int c0 = wave * 64 + l31;
        const int c1 = c0 + 32;
        const float bias0 = ba[c0];
        const float bias1 = ba[c1];
        #pragma unroll
        for (int t = 0; t < 16; ++t) {
            int rloc = (t & 3) + 8 * (t >> 2) + 4 * lh;
            hid[rloc * K2P + c0]        = f2bf(fmaxf(acc00[t] + bias0, 0.f));
            hid[rloc * K2P + c1]        = f2bf(fmaxf(acc01[t] + bias1, 0.f));
            hid[(rloc + 32) * K2P + c0] = f2bf(fmaxf(acc10[t] + bias0, 0.f));
            hid[(rloc + 32) * K2P + c1] = f2bf(fmaxf(acc11[t] + bias1, 0.f));
        }
    }
    __syncthreads();

    // ---------------- stage 2 ----------------
    if (!LSM) {
        // OUT = 128: wave -> cols wave*32..+31, 2 row tiles
        f32x16 d0 = {}, d1 = {};
        const unsigned short* wb = WbT + (size_t)(wave * 32 + l31) * 256 + lh * 8;
        const int h0 = l31 * K2P + lh * 8;
        #pragma unroll
        for (int s = 0; s < 16; ++s) {
            s16x8 a0 = *(const s16x8*)&hid[h0 + s * 16];
            s16x8 a1 = *(const s16x8*)&hid[h0 + 32 * K2P + s * 16];
            s16x8 b  = *(const s16x8*)(wb + s * 16);
            d0 = __builtin_amdgcn_mfma_f32_32x32x16_bf16(a0, b, d0, 0, 0, 0);
            d1 = __builtin_amdgcn_mfma_f32_32x32x16_bf16(a1, b, d1, 0, 0, 0);
        }
        const int col = wave * 32 + l31;
        const float bias = bb[col];
        unsigned short* out = (unsigned short*)outv;
        #pragma unroll
        for (int t = 0; t < 16; ++t) {
            int rloc = (t & 3) + 8 * (t >> 2) + 4 * lh;
            int rr0 = row0 + rloc, rr1 = rr0 + 32;
            if (rr0 < n) out[(size_t)rr0 * 128 + col] = f2bf(fmaxf(d0[t] + bias, 0.f));
            if (rr1 < n) out[(size_t)rr1 * 128 + col] = f2bf(fmaxf(d1[t] + bias, 0.f));
        }
    } else {
        // OUT = 40 (padded 64): wave quadrants (rt = wave&1, ct = wave>>1)
        const int rt = wave & 1, ct = wave >> 1;
        f32x16 d = {};
        const unsigned short* wb = WbT + (size_t)(ct * 32 + l31) * 256 + lh * 8;
        const int h0 = (rt * 32 + l31) * K2P + lh * 8;
        #pragma unroll
        for (int s = 0; s < 16; ++s) {
            s16x8 a = *(const s16x8*)&hid[h0 + s * 16];
            s16x8 b = *(const s16x8*)(wb + s * 16);
            d = __builtin_amdgcn_mfma_f32_32x32x16_bf16(a, b, d, 0, 0, 0);
        }
        __syncthreads();                    // done reading hid; reuse as logits
        float* lg = (float*)hid;            // [64][68] f32 = 17.4KB <= 33.8KB
        const int col = ct * 32 + l31;
        const float bias = (col < 40) ? bb[col] : 0.f;
        #pragma unroll
        for (int t = 0; t < 16; ++t) {
            int rloc = rt * 32 + (t & 3) + 8 * (t >> 2) + 4 * lh;
            lg[rloc * 68 + col] = d[t] + bias;
        }
        __syncthreads();
        // log_softmax over cols 0..39: 4 threads/row, 10 cols each
        const int r = tid >> 2, j = tid & 3;
        float mx = -1e30f;
        #pragma unroll
        for (int c = 0; c < 10; ++c) mx = fmaxf(mx, lg[r * 68 + j * 10 + c]);
        mx = fmaxf(mx, __shfl_xor(mx, 1));
        mx = fmaxf(mx, __shfl_xor(mx, 2));
        float sm = 0.f;
        #pragma unroll
        for (int c = 0; c < 10; ++c) sm += __expf(lg[r * 68 + j * 10 + c] - mx);
        sm += __shfl_xor(sm, 1);
        sm += __shfl_xor(sm, 2);
        const float lse = mx + __logf(sm);
        const int row = row0 + r;
        float* out = (float*)outv;
        if (row < n) {
            #pragma unroll
            for (int c = 0; c < 10; ++c)
                out[(size_t)row * 40 + j * 10 + c] = lg[r * 68 + j * 10 + c] - lse;
        }
    }
}

// ===========================================================================
extern "C" void kernel_launch(void* const* d_in, const int* in_sizes, int n_in,
                              void* d_out, int out_size, void* d_ws, size_t ws_size,
                              hipStream_t stream) {
    const float* x   = (const float*)d_in[0];
    const int*   ei  = (const int*)d_in[1];
    const float* W1a = (const float*)d_in[2];
    const float* b1a = (const float*)d_in[3];
    const float* W1b = (const float*)d_in[4];
    const float* b1b = (const float*)d_in[5];
    const float* W2a = (const float*)d_in[6];
    const float* b2a = (const float*)d_in[7];
    const float* W2b = (const float*)d_in[8];
    const float* b2b = (const float*)d_in[9];
    const float* W3a = (const float*)d_in[10];
    const float* b3a = (const float*)d_in[11];
    const float* W3b = (const float*)d_in[12];
    const float* b3b = (const float*)d_in[13];
    float* out = (float*)d_out;

    const int E = in_sizes[1] / 2;
    const int N = in_sizes[0] / 48;
    const int* src = ei;
    const int* dst = ei + E;

    // ---- workspace carve-up (256B aligned) ----
    char* p = (char*)d_ws;
    auto alloc = [&](size_t bytes) { void* q = p; p += (bytes + 255) & ~(size_t)255; return q; };
    unsigned short* xbf  = (unsigned short*)alloc((size_t)N * 48  * 2);
    unsigned short* c1   = (unsigned short*)alloc((size_t)N * 48  * 2);
    unsigned short* h1   = (unsigned short*)alloc((size_t)N * 128 * 2);
    unsigned short* c2   = (unsigned short*)alloc((size_t)N * 128 * 2);  // also c3
    unsigned short* h2   = (unsigned short*)alloc((size_t)N * 128 * 2);
    unsigned short* W1aT = (unsigned short*)alloc((size_t)256 * 96  * 2);
    unsigned short* W1bT = (unsigned short*)alloc((size_t)128 * 256 * 2);
    unsigned short* W2aT = (unsigned short*)alloc((size_t)256 * 304 * 2);
    unsigned short* W2bT = (unsigned short*)alloc((size_t)128 * 256 * 2);
    unsigned short* W3aT = (unsigned short*)alloc((size_t)256 * 304 * 2);
    unsigned short* W3bT = (unsigned short*)alloc((size_t)64  * 256 * 2);
    int* deg     = (int*)alloc((size_t)N * 4);
    int* rowptr  = (int*)alloc((size_t)N * 4);
    int* cursor  = (int*)alloc((size_t)N * 4);
    int* bsum    = (int*)alloc(1024);
    int* csr_src = (int*)alloc((size_t)E * 4);

    const int nb_scan = (N + 1023) / 1024;
    const int nblk    = (N + 63) / 64;

    // ---- prep: bf16 conversions ----
    f32_to_bf16k<<<(N * 48 + 255) / 256, 256, 0, stream>>>(x, xbf, N * 48);
    wt_transpose<<<(256 * 96  + 255) / 256, 256, 0, stream>>>(W1a, W1aT, 96,  256, 256);
    wt_transpose<<<(128 * 256 + 255) / 256, 256, 0, stream>>>(W1b, W1bT, 256, 128, 128);
    wt_transpose<<<(256 * 304 + 255) / 256, 256, 0, stream>>>(W2a, W2aT, 304, 256, 256);
    wt_transpose<<<(128 * 256 + 255) / 256, 256, 0, stream>>>(W2b, W2bT, 256, 128, 128);
    wt_transpose<<<(256 * 304 + 255) / 256, 256, 0, stream>>>(W3a, W3aT, 304, 256, 256);
    wt_transpose<<<(64  * 256 + 255) / 256, 256, 0, stream>>>(W3b, W3bT, 256, 40,  64);

    // ---- CSR build ----
    hipMemsetAsync(deg, 0, (size_t)N * sizeof(int), stream);
    deg_hist<<<(E + 255) / 256, 256, 0, stream>>>(dst, deg, E);
    scan_block_sums<<<nb_scan, 256, 0, stream>>>(deg, bsum, N);
    scan_bsums<<<1, 256, 0, stream>>>(bsum, nb_scan);
    scan_finalize<<<nb_scan, 256, 0, stream>>>(deg, bsum, rowptr, cursor, N);
    csr_scatter<<<(E + 255) / 256, 256, 0, stream>>>(src, dst, cursor, csr_src, E);

    // ---- layer 1 ----
    lgconv_gather_bf16<48, 8><<<((size_t)N * 8 + 255) / 256, 256, 0, stream>>>(
        xbf, rowptr, deg, csr_src, c1, N);
    fused_mlp_mfma<48, 48, 0, false><<<nblk, 256, 0, stream>>>(
        c1, xbf, (const unsigned short*)nullptr, W1aT, b1a, W1bT, b1b, h1, N);

    // ---- layer 2 ----
    lgconv_gather_bf16<128, 16><<<((size_t)N * 16 + 255) / 256, 256, 0, stream>>>(
        h1, rowptr, deg, csr_src, c2, N);
    fused_mlp_mfma<128, 128, 48, false><<<nblk, 256, 0, stream>>>(
        c2, h1, xbf, W2aT, b2a, W2bT, b2b, h2, N);

    // ---- layer 3 ----
    lgconv_gather_bf16<128, 16><<<((size_t)N * 16 + 255) / 256, 256, 0, stream>>>(
        h2, rowptr, deg, csr_src, c2, N);   // c3 reuses c2 slot
    fused_mlp_mfma<128, 128, 48, true><<<nblk, 256, 0, stream>>>(
        c2, h2, xbf, W3aT, b3a, W3bT, b3b, out, N);
}

// Round 7
// 583.853 us; speedup vs baseline: 13.3138x; 1.0705x over previous
//
#include <hip/hip_runtime.h>
#include <math.h>

typedef __attribute__((ext_vector_type(8)))  short s16x8;   // 8 bf16 (4 VGPRs)
typedef __attribute__((ext_vector_type(16))) float f32x16;  // MFMA 32x32 acc

__device__ inline float bf_lo(unsigned u) { return __uint_as_float(u << 16); }
__device__ inline float bf_hi(unsigned u) { return __uint_as_float(u & 0xffff0000u); }
__device__ inline unsigned short f2bf(float f) {           // RNE f32 -> bf16
    unsigned u = __float_as_uint(f);
    u += 0x7fffu + ((u >> 16) & 1u);
    return (unsigned short)(u >> 16);
}

// ===========================================================================
// Fused prep: x f32->bf16, 6 weight transposes ([K][Nc] f32 -> [Np][K] bf16,
// zero-padded), deg zeroing. One dispatch instead of 8.
// ===========================================================================
__global__ __launch_bounds__(256)
void prep_fused(const float* __restrict__ x,   unsigned short* __restrict__ xbf,
                const float* __restrict__ W1a, unsigned short* __restrict__ W1aT,
                const float* __restrict__ W1b, unsigned short* __restrict__ W1bT,
                const float* __restrict__ W2a, unsigned short* __restrict__ W2aT,
                const float* __restrict__ W2b, unsigned short* __restrict__ W2bT,
                const float* __restrict__ W3a, unsigned short* __restrict__ W3aT,
                const float* __restrict__ W3b, unsigned short* __restrict__ W3bT,
                int* __restrict__ deg, int N) {
    int i = blockIdx.x * 256 + threadIdx.x;
    int nx = N * 48;
    if (i < nx) { xbf[i] = f2bf(x[i]); return; }
    i -= nx;
    if (i < N) { deg[i] = 0; return; }
    i -= N;
    if (i < 256 * 96)  { int n = i / 96,  k = i - n * 96;  W1aT[i] = f2bf(W1a[(size_t)k * 256 + n]); return; }
    i -= 256 * 96;
    if (i < 128 * 256) { int n = i / 256, k = i - n * 256; W1bT[i] = f2bf(W1b[(size_t)k * 128 + n]); return; }
    i -= 128 * 256;
    if (i < 256 * 304) { int n = i / 304, k = i - n * 304; W2aT[i] = f2bf(W2a[(size_t)k * 256 + n]); return; }
    i -= 256 * 304;
    if (i < 128 * 256) { int n = i / 256, k = i - n * 256; W2bT[i] = f2bf(W2b[(size_t)k * 128 + n]); return; }
    i -= 128 * 256;
    if (i < 256 * 304) { int n = i / 304, k = i - n * 304; W3aT[i] = f2bf(W3a[(size_t)k * 256 + n]); return; }
    i -= 256 * 304;
    if (i < 64 * 256)  { int n = i / 256, k = i - n * 256;
                         float v = (n < 40) ? W3b[(size_t)k * 40 + n] : 0.f;
                         W3bT[i] = f2bf(v); return; }
}

// ===========================================================================
// CSR build (by dst)
// ===========================================================================
__global__ __launch_bounds__(256)
void deg_hist(const int* __restrict__ dst, int* __restrict__ deg, int E) {
    int i = blockIdx.x * 256 + threadIdx.x;
    if (i < E) atomicAdd(&deg[dst[i]], 1);
}

__global__ __launch_bounds__(256)
void scan_block_sums(const int* __restrict__ deg, int* __restrict__ bsum, int N) {
    __shared__ int sh[256];
    int base = blockIdx.x * 1024 + threadIdx.x * 4;
    int s = 0;
    #pragma unroll
    for (int k = 0; k < 4; ++k) { int i = base + k; if (i < N) s += deg[i]; }
    sh[threadIdx.x] = s;
    __syncthreads();
    for (int off = 128; off >= 1; off >>= 1) {
        if (threadIdx.x < off) sh[threadIdx.x] += sh[threadIdx.x + off];
        __syncthreads();
    }
    if (threadIdx.x == 0) bsum[blockIdx.x] = sh[0];
}

__global__ __launch_bounds__(256)
void scan_bsums(int* __restrict__ bsum, int nb) {
    __shared__ int sh[256];
    int t = threadIdx.x;
    int v = (t < nb) ? bsum[t] : 0;
    sh[t] = v;
    __syncthreads();
    for (int off = 1; off < 256; off <<= 1) {
        int add = (t >= off) ? sh[t - off] : 0;
        __syncthreads();
        sh[t] += add;
        __syncthreads();
    }
    if (t < nb) bsum[t] = sh[t] - v;
}

__global__ __launch_bounds__(256)
void scan_finalize(const int* __restrict__ deg, const int* __restrict__ bsum,
                   int* __restrict__ rowptr, int* __restrict__ cursor, int N) {
    __shared__ int sh[256];
    int t = threadIdx.x;
    int base = blockIdx.x * 1024 + t * 4;
    int loc[4];
    int s = 0;
    #pragma unroll
    for (int k = 0; k < 4; ++k) {
        int i = base + k;
        loc[k] = (i < N) ? deg[i] : 0;
        s += loc[k];
    }
    sh[t] = s;
    __syncthreads();
    for (int off = 1; off < 256; off <<= 1) {
        int add = (t >= off) ? sh[t - off] : 0;
        __syncthreads();
        sh[t] += add;
        __syncthreads();
    }
    int run = bsum[blockIdx.x] + sh[t] - s;
    #pragma unroll
    for (int k = 0; k < 4; ++k) {
        int i = base + k;
        if (i < N) { rowptr[i] = run; cursor[i] = run; }
        run += loc[k];
    }
}

// Phased scatter: phase p places only dst in [p*chunk,(p+1)*chunk).
// Active cursor slice (~50KB) + active csr region (~800KB) stay L2-resident,
// so partial lines accumulate instead of thrashing to HBM. Each block
// revisits the SAME edge slice every phase -> dst/src slices are L1-hits.
// pos<E guard: insurance against profiler single-dispatch replay with an
// advanced cursor (costs one cmp against an atomic-latency-bound loop).
__global__ __launch_bounds__(256)
void csr_scatter_phased(const int* __restrict__ src, const int* __restrict__ dst,
                        int* __restrict__ cursor, int* __restrict__ csr_src,
                        int E, int N) {
    const int P = 8;
    const int chunk = (N + P - 1) / P;
    const int stride = gridDim.x * 256;
    const int t0 = blockIdx.x * 256 + threadIdx.x;
    for (int ph = 0; ph < P; ++ph) {
        const int lo = ph * chunk;
        const int hi = min(lo + chunk, N);
        for (int e = t0; e < E; e += stride) {
            int d = dst[e];
            if (d >= lo && d < hi) {
                int pos = atomicAdd(&cursor[d], 1);
                if (pos < E) csr_src[pos] = src[e];
            }
        }
    }
}

// ===========================================================================
// LGConv gather, bf16 in/out, f32 accumulate. 8 channels (16B) per lane.
// ===========================================================================
template<int D, int LPN>
__global__ __launch_bounds__(256)
void lgconv_gather_bf16(const unsigned short* __restrict__ x,
                        const int* __restrict__ rowptr,
                        const int* __restrict__ deg,
                        const int* __restrict__ csr_src,
                        unsigned short* __restrict__ out, int N) {
    const int g    = (blockIdx.x * 256 + threadIdx.x) / LPN;
    const int lane = threadIdx.x & (LPN - 1);
    if (g >= N) return;
    if (lane * 8 >= D) return;
    const int start = rowptr[g];
    const int dg    = deg[g];
    float acc[8] = {0.f,0.f,0.f,0.f,0.f,0.f,0.f,0.f};
    int j = 0;
    for (; j + 1 < dg; j += 2) {
        int s0 = csr_src[start + j];
        int s1 = csr_src[start + j + 1];
        uint4 v0 = *(const uint4*)(x + (size_t)s0 * D + lane * 8);
        uint4 v1 = *(const uint4*)(x + (size_t)s1 * D + lane * 8);
        acc[0] += bf_lo(v0.x); acc[1] += bf_hi(v0.x);
        acc[2] += bf_lo(v0.y); acc[3] += bf_hi(v0.y);
        acc[4] += bf_lo(v0.z); acc[5] += bf_hi(v0.z);
        acc[6] += bf_lo(v0.w); acc[7] += bf_hi(v0.w);
        acc[0] += bf_lo(v1.x); acc[1] += bf_hi(v1.x);
        acc[2] += bf_lo(v1.y); acc[3] += bf_hi(v1.y);
        acc[4] += bf_lo(v1.z); acc[5] += bf_hi(v1.z);
        acc[6] += bf_lo(v1.w); acc[7] += bf_hi(v1.w);
    }
    if (j < dg) {
        int s0 = csr_src[start + j];
        uint4 v0 = *(const uint4*)(x + (size_t)s0 * D + lane * 8);
        acc[0] += bf_lo(v0.x); acc[1] += bf_hi(v0.x);
        acc[2] += bf_lo(v0.y); acc[3] += bf_hi(v0.y);
        acc[4] += bf_lo(v0.z); acc[5] += bf_hi(v0.z);
        acc[6] += bf_lo(v0.w); acc[7] += bf_hi(v0.w);
    }
    uint4 o;
    o.x = ((unsigned)f2bf(acc[1]) << 16) | f2bf(acc[0]);
    o.y = ((unsigned)f2bf(acc[3]) << 16) | f2bf(acc[2]);
    o.z = ((unsigned)f2bf(acc[5]) << 16) | f2bf(acc[4]);
    o.w = ((unsigned)f2bf(acc[7]) << 16) | f2bf(acc[6]);
    *(uint4*)(out + (size_t)g * D + lane * 8) = o;
}

// ===========================================================================
// Fused 2-layer MLP, bf16 MFMA (32x32x16), 64 rows/block, 4 waves.
// (unchanged from round 4 — verified correct, absmax 2.0)
// ===========================================================================
template<int LA, int LB, int LC, bool LSM>
__global__ __launch_bounds__(256)
void fused_mlp_mfma(const unsigned short* __restrict__ segA,
                    const unsigned short* __restrict__ segB,
                    const unsigned short* __restrict__ segC,
                    const unsigned short* __restrict__ WaT, const float* __restrict__ ba,
                    const unsigned short* __restrict__ WbT, const float* __restrict__ bb,
                    void* __restrict__ outv, int n) {
    constexpr int K1  = LA + LB + LC;       // 96 or 304
    constexpr int NS1 = K1 / 16;
    constexpr int K2P = 264;                // 256 + 8 (rows stay 16B-aligned)
    __shared__ __attribute__((aligned(16))) unsigned short hid[64 * K2P];

    const int tid  = threadIdx.x;
    const int wave = tid >> 6;
    const int lane = tid & 63;
    const int l31  = lane & 31;
    const int lh   = lane >> 5;
    const int row0 = blockIdx.x * 64;

    const int r0  = row0 + l31;
    const int r1  = r0 + 32;
    const int ra0 = (r0 < n) ? r0 : (n - 1);
    const int ra1 = (r1 < n) ? r1 : (n - 1);

    // ---------------- stage 1 ----------------
    f32x16 acc00 = {}, acc01 = {}, acc10 = {}, acc11 = {};
    const unsigned short* wa0 = WaT + (size_t)(wave * 64 + l31) * K1 + lh * 8;
    const unsigned short* wa1 = wa0 + (size_t)32 * K1;

    #pragma unroll
    for (int s = 0; s < NS1; ++s) {
        const int k0 = s * 16;              // compile-time; segment-uniform
        const unsigned short* ap;
        int strd, off;
        if (k0 < LA)           { ap = segA; strd = LA; off = k0; }
        else if (k0 < LA + LB) { ap = segB; strd = LB; off = k0 - LA; }
        else                   { ap = segC; strd = LC; off = k0 - LA - LB; }
        s16x8 a0 = *(const s16x8*)(ap + (size_t)ra0 * strd + off + lh * 8);
        s16x8 a1 = *(const s16x8*)(ap + (size_t)ra1 * strd + off + lh * 8);
        s16x8 b0 = *(const s16x8*)(wa0 + k0);
        s16x8 b1 = *(const s16x8*)(wa1 + k0);
        acc00 = __builtin_amdgcn_mfma_f32_32x32x16_bf16(a0, b0, acc00, 0, 0, 0);
        acc01 = __builtin_amdgcn_mfma_f32_32x32x16_bf16(a0, b1, acc01, 0, 0, 0);
        acc10 = __builtin_amdgcn_mfma_f32_32x32x16_bf16(a1, b0, acc10, 0, 0, 0);
        acc11 = __builtin_amdgcn_mfma_f32_32x32x16_bf16(a1, b1, acc11, 0, 0, 0);
    }

    // epilogue: + bias, relu -> hid[m][k] bf16
    {
        const int c0 = wave * 64 + l31;
        const int c1 = c0 + 32;
        const float bias0 = ba[c0];
        const float bias1 = ba[c1];
        #pragma unroll
        for (int t = 0; t < 16; ++t) {
            int rloc = (t & 3) + 8 * (t >> 2) + 4 * lh;
            hid[rloc * K2P + c0]        = f2bf(fmaxf(acc00[t] + bias0, 0.f));
            hid[rloc * K2P + c1]        = f2bf(fmaxf(acc01[t] + bias1, 0.f));
            hid[(rloc + 32) * K2P + c0] = f2bf(fmaxf(acc10[t] + bias0, 0.f));
            hid[(rloc + 32) * K2P + c1] = f2bf(fmaxf(acc11[t] + bias1, 0.f));
        }
    }
    __syncthreads();

    // ---------------- stage 2 ----------------
    if (!LSM) {
        f32x16 d0 = {}, d1 = {};
        const unsigned short* wb = WbT + (size_t)(wave * 32 + l31) * 256 + lh * 8;
        const int h0 = l31 * K2P + lh * 8;
        #pragma unroll
        for (int s = 0; s < 16; ++s) {
            s16x8 a0 = *(const s16x8*)&hid[h0 + s * 16];
            s16x8 a1 = *(const s16x8*)&hid[h0 + 32 * K2P + s * 16];
            s16x8 b  = *(const s16x8*)(wb + s * 16);
            d0 = __builtin_amdgcn_mfma_f32_32x32x16_bf16(a0, b, d0, 0, 0, 0);
            d1 = __builtin_amdgcn_mfma_f32_32x32x16_bf16(a1, b, d1, 0, 0, 0);
        }
        const int col = wave * 32 + l31;
        const float bias = bb[col];
        unsigned short* out = (unsigned short*)outv;
        #pragma unroll
        for (int t = 0; t < 16; ++t) {
            int rloc = (t & 3) + 8 * (t >> 2) + 4 * lh;
            int rr0 = row0 + rloc, rr1 = rr0 + 32;
            if (rr0 < n) out[(size_t)rr0 * 128 + col] = f2bf(fmaxf(d0[t] + bias, 0.f));
            if (rr1 < n) out[(size_t)rr1 * 128 + col] = f2bf(fmaxf(d1[t] + bias, 0.f));
        }
    } else {
        const int rt = wave & 1, ct = wave >> 1;
        f32x16 d = {};
        const unsigned short* wb = WbT + (size_t)(ct * 32 + l31) * 256 + lh * 8;
        const int h0 = (rt * 32 + l31) * K2P + lh * 8;
        #pragma unroll
        for (int s = 0; s < 16; ++s) {
            s16x8 a = *(const s16x8*)&hid[h0 + s * 16];
            s16x8 b = *(const s16x8*)(wb + s * 16);
            d = __builtin_amdgcn_mfma_f32_32x32x16_bf16(a, b, d, 0, 0, 0);
        }
        __syncthreads();                    // done reading hid; reuse as logits
        float* lg = (float*)hid;            // [64][68] f32 = 17.4KB <= 33.8KB
        const int col = ct * 32 + l31;
        const float bias = (col < 40) ? bb[col] : 0.f;
        #pragma unroll
        for (int t = 0; t < 16; ++t) {
            int rloc = rt * 32 + (t & 3) + 8 * (t >> 2) + 4 * lh;
            lg[rloc * 68 + col] = d[t] + bias;
        }
        __syncthreads();
        const int r = tid >> 2, j = tid & 3;
        float mx = -1e30f;
        #pragma unroll
        for (int c = 0; c < 10; ++c) mx = fmaxf(mx, lg[r * 68 + j * 10 + c]);
        mx = fmaxf(mx, __shfl_xor(mx, 1));
        mx = fmaxf(mx, __shfl_xor(mx, 2));
        float sm = 0.f;
        #pragma unroll
        for (int c = 0; c < 10; ++c) sm += __expf(lg[r * 68 + j * 10 + c] - mx);
        sm += __shfl_xor(sm, 1);
        sm += __shfl_xor(sm, 2);
        const float lse = mx + __logf(sm);
        const int row = row0 + r;
        float* out = (float*)outv;
        if (row < n) {
            #pragma unroll
            for (int c = 0; c < 10; ++c)
                out[(size_t)row * 40 + j * 10 + c] = lg[r * 68 + j * 10 + c] - lse;
        }
    }
}

// ===========================================================================
extern "C" void kernel_launch(void* const* d_in, const int* in_sizes, int n_in,
                              void* d_out, int out_size, void* d_ws, size_t ws_size,
                              hipStream_t stream) {
    const float* x   = (const float*)d_in[0];
    const int*   ei  = (const int*)d_in[1];
    const float* W1a = (const float*)d_in[2];
    const float* b1a = (const float*)d_in[3];
    const float* W1b = (const float*)d_in[4];
    const float* b1b = (const float*)d_in[5];
    const float* W2a = (const float*)d_in[6];
    const float* b2a = (const float*)d_in[7];
    const float* W2b = (const float*)d_in[8];
    const float* b2b = (const float*)d_in[9];
    const float* W3a = (const float*)d_in[10];
    const float* b3a = (const float*)d_in[11];
    const float* W3b = (const float*)d_in[12];
    const float* b3b = (const float*)d_in[13];
    float* out = (float*)d_out;

    const int E = in_sizes[1] / 2;
    const int N = in_sizes[0] / 48;
    const int* src = ei;
    const int* dst = ei + E;

    // ---- workspace carve-up (256B aligned) ----
    char* p = (char*)d_ws;
    auto alloc = [&](size_t bytes) { void* q = p; p += (bytes + 255) & ~(size_t)255; return q; };
    unsigned short* xbf  = (unsigned short*)alloc((size_t)N * 48  * 2);
    unsigned short* c1   = (unsigned short*)alloc((size_t)N * 48  * 2);
    unsigned short* h1   = (unsigned short*)alloc((size_t)N * 128 * 2);
    unsigned short* c2   = (unsigned short*)alloc((size_t)N * 128 * 2);  // also c3
    unsigned short* h2   = (unsigned short*)alloc((size_t)N * 128 * 2);
    unsigned short* W1aT = (unsigned short*)alloc((size_t)256 * 96  * 2);
    unsigned short* W1bT = (unsigned short*)alloc((size_t)128 * 256 * 2);
    unsigned short* W2aT = (unsigned short*)alloc((size_t)256 * 304 * 2);
    unsigned short* W2bT = (unsigned short*)alloc((size_t)128 * 256 * 2);
    unsigned short* W3aT = (unsigned short*)alloc((size_t)256 * 304 * 2);
    unsigned short* W3bT = (unsigned short*)alloc((size_t)64  * 256 * 2);
    int* deg     = (int*)alloc((size_t)N * 4);
    int* rowptr  = (int*)alloc((size_t)N * 4);
    int* cursor  = (int*)alloc((size_t)N * 4);
    int* bsum    = (int*)alloc(1024);
    int* csr_src = (int*)alloc((size_t)E * 4);

    const int nb_scan = (N + 1023) / 1024;
    const int nblk    = (N + 63) / 64;

    // ---- fused prep (x->bf16, 6 transposes, deg=0) ----
    {
        int total = N * 48 + N + 256*96 + 128*256 + 256*304 + 128*256 + 256*304 + 64*256;
        prep_fused<<<(total + 255) / 256, 256, 0, stream>>>(
            x, xbf, W1a, W1aT, W1b, W1bT, W2a, W2aT, W2b, W2bT,
            W3a, W3aT, W3b, W3bT, deg, N);
    }

    // ---- CSR build ----
    deg_hist<<<(E + 255) / 256, 256, 0, stream>>>(dst, deg, E);
    scan_block_sums<<<nb_scan, 256, 0, stream>>>(deg, bsum, N);
    scan_bsums<<<1, 256, 0, stream>>>(bsum, nb_scan);
    scan_finalize<<<nb_scan, 256, 0, stream>>>(deg, bsum, rowptr, cursor, N);
    csr_scatter_phased<<<2048, 256, 0, stream>>>(src, dst, cursor, csr_src, E, N);

    // ---- layer 1 ----
    lgconv_gather_bf16<48, 8><<<((size_t)N * 8 + 255) / 256, 256, 0, stream>>>(
        xbf, rowptr, deg, csr_src, c1, N);
    fused_mlp_mfma<48, 48, 0, false><<<nblk, 256, 0, stream>>>(
        c1, xbf, (const unsigned short*)nullptr, W1aT, b1a, W1bT, b1b, h1, N);

    // ---- layer 2 ----
    lgconv_gather_bf16<128, 16><<<((size_t)N * 16 + 255) / 256, 256, 0, stream>>>(
        h1, rowptr, deg, csr_src, c2, N);
    fused_mlp_mfma<128, 128, 48, false><<<nblk, 256, 0, stream>>>(
        c2, h1, xbf, W2aT, b2a, W2bT, b2b, h2, N);

    // ---- layer 3 ----
    lgconv_gather_bf16<128, 16><<<((size_t)N * 16 + 255) / 256, 256, 0, stream>>>(
        h2, rowptr, deg, csr_src, c2, N);   // c3 reuses c2 slot
    fused_mlp_mfma<128, 128, 48, true><<<nblk, 256, 0, stream>>>(
        c2, h2, xbf, W3aT, b3a, W3bT, b3b, out, N);
}